// Round 6
// baseline (49.660 us; speedup 1.0000x reference)
//
#include <hip/hip_runtime.h>
#include <math.h>

#define HW (1024*1024)
#define BATCH 16

typedef float fx4 __attribute__((ext_vector_type(4)));

// Single fused kernel, producer-wave design.
//   waves 0-3 (t<256): workers — issue 8x dwordx4 weight loads immediately,
//     then wait at barrier while loads fly.
//   wave 4 (t>=256): producer — computes the 192 param floats into LDS
//     (3 dot-products of length 64 per lane; intra-wave LDS ordering only),
//     folds to per-(batch,channel) complex affine coeffs.
// Math fold: caddmul(clerp(w0,w1,l), s, bias) = w0*s*(1-l) + w1*s*l + bias,
// so A = s*(1-l), B = s*l, C = bias. sp: [16][2][6] = {Ar,Ai,Br,Bi,Cr,Ci}
__global__ __launch_bounds__(320, 5) void fused_kernel(
    const float* __restrict__ x,       // [16][64]
    const float* __restrict__ W_in,    // [12][64]
    const float* __restrict__ b_in,    // [12]
    const float* __restrict__ W_gate,  // [12][64]
    const float* __restrict__ b_gate,  // [12]
    const float* __restrict__ wts,     // [2][2][HW][2]
    float* __restrict__ out)           // [16][HW]
{
    __shared__ float smod[BATCH][12];
    __shared__ float sp[192];
    const int t = threadIdx.x;

    float4 Wv[4][2];
    int idx = 0;
    if (t < 256) {
        // ---- workers: issue weight loads (4 px/thread, 2 float4 per jc) ----
        idx = blockIdx.x * 256 + t;              // 0 .. HW/4 - 1
        const float4* w4 = (const float4*)wts;   // [jc][HW/2] float4s
#pragma unroll
        for (int jc = 0; jc < 4; ++jc) {
            Wv[jc][0] = w4[jc * (HW / 2) + idx * 2 + 0];
            Wv[jc][1] = w4[jc * (HW / 2) + idx * 2 + 1];
        }
    } else {
        // ---- producer wave: params into LDS ----
        const int u = t - 256;                   // 0..63
#pragma unroll
        for (int r = 0; r < 3; ++r) {
            int id = u * 3 + r;                  // 0..191
            int b = id / 12, j = id % 12;
            const float4* x4  = (const float4*)(x + b * 64);
            const float4* wi4 = (const float4*)(W_in + j * 64);
            const float4* wg4 = (const float4*)(W_gate + j * 64);
            float xt = b_in[j], xg = b_gate[j];
#pragma unroll
            for (int k = 0; k < 16; ++k) {
                float4 xv = x4[k], wi = wi4[k], wg = wg4[k];
                xt = fmaf(xv.x, wi.x, xt); xg = fmaf(xv.x, wg.x, xg);
                xt = fmaf(xv.y, wi.y, xt); xg = fmaf(xv.y, wg.y, xg);
                xt = fmaf(xv.z, wi.z, xt); xg = fmaf(xv.z, wg.z, xg);
                xt = fmaf(xv.w, wi.w, xt); xg = fmaf(xv.w, wg.w, xg);
            }
            smod[b][j] = xt * tanhf(xg);
        }
        // fold (same wave wrote smod -> in-order LDS, no barrier needed)
        if (u < 32) {
            int bb = u >> 1, c = u & 1;
            float l0 = smod[bb][0 + c * 2 + 0] + 0.5f;
            float l1 = smod[bb][0 + c * 2 + 1];
            float br = smod[bb][4 + c * 2 + 0];
            float bi = smod[bb][4 + c * 2 + 1];
            float s0 = smod[bb][8 + c * 2 + 0] + 1.0f;
            float s1 = smod[bb][8 + c * 2 + 1];
            float omr = 1.0f - l0, omi = -l1;    // (1 - l)
            float Ar = s0 * omr - s1 * omi;
            float Ai = s0 * omi + s1 * omr;
            float Br = s0 * l0 - s1 * l1;
            float Bi = s0 * l1 + s1 * l0;
            float* p = sp + u * 6;               // u == bb*2 + c
            p[0] = Ar; p[1] = Ai; p[2] = Br; p[3] = Bi; p[4] = br; p[5] = bi;
        }
    }
    __syncthreads();
    if (t >= 256) return;

    const float* w00 = (const float*)Wv[0];  // j=0, c=0
    const float* w01 = (const float*)Wv[1];  // j=0, c=1
    const float* w10 = (const float*)Wv[2];  // j=1, c=0
    const float* w11 = (const float*)Wv[3];  // j=1, c=1

    float4* out4 = (float4*)out;
#pragma unroll
    for (int b = 0; b < BATCH; ++b) {
        const fx4* q = (const fx4*)(sp + b * 12);
        fx4 q0 = q[0];   // A0r A0i B0r B0i   (c=0)
        fx4 q1 = q[1];   // C0r C0i A1r A1i
        fx4 q2 = q[2];   // B1r B1i C1r C1i
        float A0r = q0[0], A0i = q0[1], B0r = q0[2], B0i = q0[3];
        float c0r = q1[0], c0i = q1[1], A1r = q1[2], A1i = q1[3];
        float B1r = q2[0], B1i = q2[1], c1r = q2[2], c1i = q2[3];

        float4 o;
        float* op = (float*)&o;
#pragma unroll
        for (int p = 0; p < 4; ++p) {
            float a0r = w00[p * 2], a0i = w00[p * 2 + 1];
            float b0r = w10[p * 2], b0i = w10[p * 2 + 1];
            float a1r = w01[p * 2], a1i = w01[p * 2 + 1];
            float b1r = w11[p * 2], b1i = w11[p * 2 + 1];
            float z0r = c0r + A0r * a0r - A0i * a0i + B0r * b0r - B0i * b0i;
            float z0i = c0i + A0r * a0i + A0i * a0r + B0r * b0i + B0i * b0r;
            float z1r = c1r + A1r * a1r - A1i * a1i + B1r * b1r - B1i * b1i;
            float z1i = c1i + A1r * a1i + A1i * a1r + B1r * b1i + B1i * b1r;
            float rs = rsqrtf(z1r * z1r + z1i * z1i + 1e-12f);
            op[p] = (z0r * z1r + z0i * z1i) * rs;
        }
        out4[b * (HW / 4) + idx] = o;
    }
}

extern "C" void kernel_launch(void* const* d_in, const int* in_sizes, int n_in,
                              void* d_out, int out_size, void* d_ws, size_t ws_size,
                              hipStream_t stream) {
    const float* x      = (const float*)d_in[0];
    const float* W_in   = (const float*)d_in[1];
    const float* b_in   = (const float*)d_in[2];
    const float* W_gate = (const float*)d_in[3];
    const float* b_gate = (const float*)d_in[4];
    const float* wts    = (const float*)d_in[5];
    float* out = (float*)d_out;

    fused_kernel<<<1024, 320, 0, stream>>>(x, W_in, b_in, W_gate, b_gate, wts, out);
}

// Round 7
// 32.838 us; speedup vs baseline: 1.5122x; 1.5122x over previous
//
#include <hip/hip_runtime.h>
#include <math.h>

#define HW (1024*1024)
#define BATCH 16

typedef float fx4 __attribute__((ext_vector_type(4)));

// Fused kernel, loads-first ordering:
//   1. every thread issues its 8 weight dwordx4 loads (900-cy HBM latency)
//   2. threads t<192 compute the params dot-products IN THE SHADOW of (1)
//      (x/W_in/W_gate are ~10 KB, L2/L3-resident after the first blocks)
//   3. barrier; t<32 folds mod -> complex affine coeffs; barrier
//   4. main loop consumes Wv from registers + coeffs from LDS broadcast.
// Math fold: caddmul(clerp(w0,w1,l), s, bias) = w0*s*(1-l) + w1*s*l + bias,
// so A = s*(1-l), B = s*l, C = bias. sp: [16][2][6] = {Ar,Ai,Br,Bi,Cr,Ci}
// NOTE: no min-waves in launch_bounds — R6 proved forcing 5 waves/EU spills
// the 32-VGPR Wv live range to scratch (+17 MB writes, 2x slower).
__global__ __launch_bounds__(256) void fused_kernel(
    const float* __restrict__ x,       // [16][64]
    const float* __restrict__ W_in,    // [12][64]
    const float* __restrict__ b_in,    // [12]
    const float* __restrict__ W_gate,  // [12][64]
    const float* __restrict__ b_gate,  // [12]
    const float* __restrict__ wts,     // [2][2][HW][2]
    float* __restrict__ out)           // [16][HW]
{
    __shared__ float smod[BATCH][12];
    __shared__ float sp[192];
    const int t = threadIdx.x;
    const int idx = blockIdx.x * 256 + t;    // 0 .. HW/4 - 1

    // ---- 1: issue weight loads (4 px/thread, 2 float4 per jc) ----
    const float4* w4 = (const float4*)wts;   // [jc][HW/2] float4s
    float4 Wv[4][2];
#pragma unroll
    for (int jc = 0; jc < 4; ++jc) {
        Wv[jc][0] = w4[jc * (HW / 2) + idx * 2 + 0];
        Wv[jc][1] = w4[jc * (HW / 2) + idx * 2 + 1];
    }

    // ---- 2: params dot-products, overlapped with the loads above ----
    if (t < 192) {
        int b = t / 12, j = t % 12;
        const float4* x4  = (const float4*)(x + b * 64);
        const float4* wi4 = (const float4*)(W_in + j * 64);
        const float4* wg4 = (const float4*)(W_gate + j * 64);
        float xt = b_in[j], xg = b_gate[j];
#pragma unroll
        for (int k = 0; k < 16; ++k) {
            float4 xv = x4[k], wi = wi4[k], wg = wg4[k];
            xt = fmaf(xv.x, wi.x, xt); xg = fmaf(xv.x, wg.x, xg);
            xt = fmaf(xv.y, wi.y, xt); xg = fmaf(xv.y, wg.y, xg);
            xt = fmaf(xv.z, wi.z, xt); xg = fmaf(xv.z, wg.z, xg);
            xt = fmaf(xv.w, wi.w, xt); xg = fmaf(xv.w, wg.w, xg);
        }
        smod[b][j] = xt * tanhf(xg);
    }
    __syncthreads();

    // ---- 3: fold to complex affine coeffs ----
    if (t < 32) {
        int bb = t >> 1, c = t & 1;
        float l0 = smod[bb][0 + c * 2 + 0] + 0.5f;
        float l1 = smod[bb][0 + c * 2 + 1];
        float br = smod[bb][4 + c * 2 + 0];
        float bi = smod[bb][4 + c * 2 + 1];
        float s0 = smod[bb][8 + c * 2 + 0] + 1.0f;
        float s1 = smod[bb][8 + c * 2 + 1];
        float omr = 1.0f - l0, omi = -l1;    // (1 - l)
        float Ar = s0 * omr - s1 * omi;
        float Ai = s0 * omi + s1 * omr;
        float Br = s0 * l0 - s1 * l1;
        float Bi = s0 * l1 + s1 * l0;
        float* p = sp + t * 6;               // t == bb*2 + c
        p[0] = Ar; p[1] = Ai; p[2] = Br; p[3] = Bi; p[4] = br; p[5] = bi;
    }
    __syncthreads();

    // ---- 4: main transform ----
    const float* w00 = (const float*)Wv[0];  // j=0, c=0
    const float* w01 = (const float*)Wv[1];  // j=0, c=1
    const float* w10 = (const float*)Wv[2];  // j=1, c=0
    const float* w11 = (const float*)Wv[3];  // j=1, c=1

    float4* out4 = (float4*)out;
#pragma unroll
    for (int b = 0; b < BATCH; ++b) {
        const fx4* q = (const fx4*)(sp + b * 12);
        fx4 q0 = q[0];   // A0r A0i B0r B0i   (c=0)
        fx4 q1 = q[1];   // C0r C0i A1r A1i
        fx4 q2 = q[2];   // B1r B1i C1r C1i
        float A0r = q0[0], A0i = q0[1], B0r = q0[2], B0i = q0[3];
        float c0r = q1[0], c0i = q1[1], A1r = q1[2], A1i = q1[3];
        float B1r = q2[0], B1i = q2[1], c1r = q2[2], c1i = q2[3];

        float4 o;
        float* op = (float*)&o;
#pragma unroll
        for (int p = 0; p < 4; ++p) {
            float a0r = w00[p * 2], a0i = w00[p * 2 + 1];
            float b0r = w10[p * 2], b0i = w10[p * 2 + 1];
            float a1r = w01[p * 2], a1i = w01[p * 2 + 1];
            float b1r = w11[p * 2], b1i = w11[p * 2 + 1];
            float z0r = c0r + A0r * a0r - A0i * a0i + B0r * b0r - B0i * b0i;
            float z0i = c0i + A0r * a0i + A0i * a0r + B0r * b0i + B0i * b0r;
            float z1r = c1r + A1r * a1r - A1i * a1i + B1r * b1r - B1i * b1i;
            float z1i = c1i + A1r * a1i + A1i * a1r + B1r * b1i + B1i * b1r;
            float rs = rsqrtf(z1r * z1r + z1i * z1i + 1e-12f);
            op[p] = (z0r * z1r + z0i * z1i) * rs;
        }
        out4[b * (HW / 4) + idx] = o;
    }
}

extern "C" void kernel_launch(void* const* d_in, const int* in_sizes, int n_in,
                              void* d_out, int out_size, void* d_ws, size_t ws_size,
                              hipStream_t stream) {
    const float* x      = (const float*)d_in[0];
    const float* W_in   = (const float*)d_in[1];
    const float* b_in   = (const float*)d_in[2];
    const float* W_gate = (const float*)d_in[3];
    const float* b_gate = (const float*)d_in[4];
    const float* wts    = (const float*)d_in[5];
    float* out = (float*)d_out;

    fused_kernel<<<1024, 256, 0, stream>>>(x, W_in, b_in, W_gate, b_gate, wts, out);
}

// Round 9
// 28.554 us; speedup vs baseline: 1.7392x; 1.1501x over previous
//
#include <hip/hip_runtime.h>
#include <math.h>

#define HW (1024*1024)
#define BATCH 16

// Kernel 1: per-(batch,channel) complex affine params -> d_ws (768 B).
// mod[b,j] = (x@W_in.T+b_in)[b,j] * tanh((x@W_gate.T+b_gate)[b,j])
// Fold: caddmul(clerp(w0,w1,l), s, bias) = w0*s*(1-l) + w1*s*l + bias,
// so A = s*(1-l), B = s*l, C = bias.  par: [16][2][6] = {Ar,Ai,Br,Bi,Cr,Ci}
__global__ __launch_bounds__(192) void params_kernel(
    const float* __restrict__ x,       // [16][64]
    const float* __restrict__ W_in,    // [12][64]
    const float* __restrict__ b_in,    // [12]
    const float* __restrict__ W_gate,  // [12][64]
    const float* __restrict__ b_gate,  // [12]
    float* __restrict__ par)           // [16][2][6]
{
    __shared__ float smod[BATCH][12];
    int t = threadIdx.x;
    int b = t / 12, j = t % 12;
    {
        const float4* x4  = (const float4*)(x + b * 64);
        const float4* wi4 = (const float4*)(W_in + j * 64);
        const float4* wg4 = (const float4*)(W_gate + j * 64);
        float xt = b_in[j], xg = b_gate[j];
#pragma unroll
        for (int k = 0; k < 16; ++k) {
            float4 xv = x4[k], wi = wi4[k], wg = wg4[k];
            xt = fmaf(xv.x, wi.x, xt); xg = fmaf(xv.x, wg.x, xg);
            xt = fmaf(xv.y, wi.y, xt); xg = fmaf(xv.y, wg.y, xg);
            xt = fmaf(xv.z, wi.z, xt); xg = fmaf(xv.z, wg.z, xg);
            xt = fmaf(xv.w, wi.w, xt); xg = fmaf(xv.w, wg.w, xg);
        }
        smod[b][j] = xt * tanhf(xg);
    }
    __syncthreads();
    if (t < 32) {
        int bb = t >> 1, c = t & 1;
        float l0 = smod[bb][0 + c * 2 + 0] + 0.5f;
        float l1 = smod[bb][0 + c * 2 + 1];
        float br = smod[bb][4 + c * 2 + 0];
        float bi = smod[bb][4 + c * 2 + 1];
        float s0 = smod[bb][8 + c * 2 + 0] + 1.0f;
        float s1 = smod[bb][8 + c * 2 + 1];
        float omr = 1.0f - l0, omi = -l1;      // (1 - l)
        float Ar = s0 * omr - s1 * omi;
        float Ai = s0 * omi + s1 * omr;
        float Br = s0 * l0 - s1 * l1;
        float Bi = s0 * l1 + s1 * l0;
        float* p = par + (bb * 2 + c) * 6;
        p[0] = Ar; p[1] = Ai; p[2] = Br; p[3] = Bi; p[4] = br; p[5] = bi;
    }
}

// Kernel 2: streaming transform. NO LDS, NO barrier: params are wave-uniform
// -> scalar loads (constant cache), hoisted by the compiler. Waves are fully
// independent; load burst / compute / store phases of neighbor waves
// interleave instead of convoying behind a block barrier.
__global__ __launch_bounds__(256) void main_kernel(
    const float* __restrict__ wts,   // [2][2][HW][2]
    const float* __restrict__ par,   // [16][2][6] = 192 floats
    float* __restrict__ out)         // [16][HW]
{
    const int t = threadIdx.x;
    const int idx = blockIdx.x * 256 + t;    // 0 .. HW/4 - 1 (4 px/thread)
    const float4* w4 = (const float4*)wts;   // [jc][HW/2] float4s

    float4 Wv[4][2];
#pragma unroll
    for (int jc = 0; jc < 4; ++jc) {
        Wv[jc][0] = w4[jc * (HW / 2) + idx * 2 + 0];
        Wv[jc][1] = w4[jc * (HW / 2) + idx * 2 + 1];
    }
    const float* w00 = (const float*)Wv[0];  // j=0, c=0
    const float* w01 = (const float*)Wv[1];  // j=0, c=1
    const float* w10 = (const float*)Wv[2];  // j=1, c=0
    const float* w11 = (const float*)Wv[3];  // j=1, c=1

    float4* out4 = (float4*)out;
#pragma unroll
    for (int b = 0; b < BATCH; ++b) {
        // uniform indices (no threadIdx) -> s_load from constant cache
        const float* p0 = par + (b * 2 + 0) * 6;
        const float* p1 = par + (b * 2 + 1) * 6;
        float A0r = p0[0], A0i = p0[1], B0r = p0[2], B0i = p0[3], c0r = p0[4], c0i = p0[5];
        float A1r = p1[0], A1i = p1[1], B1r = p1[2], B1i = p1[3], c1r = p1[4], c1i = p1[5];

        float4 o;
        float* op = (float*)&o;
#pragma unroll
        for (int p = 0; p < 4; ++p) {
            float a0r = w00[p * 2], a0i = w00[p * 2 + 1];
            float b0r = w10[p * 2], b0i = w10[p * 2 + 1];
            float a1r = w01[p * 2], a1i = w01[p * 2 + 1];
            float b1r = w11[p * 2], b1i = w11[p * 2 + 1];
            float z0r = c0r + A0r * a0r - A0i * a0i + B0r * b0r - B0i * b0i;
            float z0i = c0i + A0r * a0i + A0i * a0r + B0r * b0i + B0i * b0r;
            float z1r = c1r + A1r * a1r - A1i * a1i + B1r * b1r - B1i * b1i;
            float z1i = c1i + A1r * a1i + A1i * a1r + B1r * b1i + B1i * b1r;
            float rs = rsqrtf(z1r * z1r + z1i * z1i + 1e-12f);
            op[p] = (z0r * z1r + z0i * z1i) * rs;
        }
        out4[b * (HW / 4) + idx] = o;
    }
}

extern "C" void kernel_launch(void* const* d_in, const int* in_sizes, int n_in,
                              void* d_out, int out_size, void* d_ws, size_t ws_size,
                              hipStream_t stream) {
    const float* x      = (const float*)d_in[0];
    const float* W_in   = (const float*)d_in[1];
    const float* b_in   = (const float*)d_in[2];
    const float* W_gate = (const float*)d_in[3];
    const float* b_gate = (const float*)d_in[4];
    const float* wts    = (const float*)d_in[5];
    float* out = (float*)d_out;
    float* par = (float*)d_ws;

    params_kernel<<<1, 192, 0, stream>>>(x, W_in, b_in, W_gate, b_gate, par);
    main_kernel<<<1024, 256, 0, stream>>>(wts, par, out);
}